// Round 16
// baseline (174.114 us; speedup 1.0000x reference)
//
#include <hip/hip_runtime.h>
#include <hip/hip_bf16.h>

#define S_LEN 2048
#define D_DIM 1024
#define NHEAD 16
#define HDIM  64
#define BATCH 4
#define MROWS (BATCH*S_LEN)   /* 8192 */

typedef short bf16x8 __attribute__((ext_vector_type(8)));
typedef float f32x4  __attribute__((ext_vector_type(4)));
typedef float f32x16 __attribute__((ext_vector_type(16)));
typedef unsigned short u16;

#if __has_builtin(__builtin_amdgcn_exp2f)
#define EXP2(x) __builtin_amdgcn_exp2f(x)
#else
#define EXP2(x) __expf((x) * 0.6931471805599453f)
#endif

#define QSCALE 0.1803368801111137f   /* (1/8) * log2(e) */

__device__ inline u16 f2bf(float f) {
  union { float f; unsigned u; } v; v.f = f;
  unsigned r = v.u + 0x7fff + ((v.u >> 16) & 1);   // RNE
  return (u16)(r >> 16);
}

__device__ inline unsigned cvtpk(float lo, float hi_) {
  unsigned d;
  asm("v_cvt_pk_bf16_f32 %0, %1, %2" : "=v"(d) : "v"(lo), "v"(hi_));
  return d;
}

__device__ inline void perm32swap(unsigned& a, unsigned& b) {
  asm volatile("v_permlane32_swap_b32 %0, %1" : "+v"(a), "+v"(b));
}

__device__ inline void gload_lds16(const void* g, void* l) {
  __builtin_amdgcn_global_load_lds(
      (const __attribute__((address_space(1))) void*)g,
      (__attribute__((address_space(3))) void*)l, 16, 0, 0);
}

// ---------------- fused prep: X fp32->bf16 + 4 weight transposes ----------------
__global__ __launch_bounds__(256) void prep_kernel(
    const float* __restrict__ x, u16* __restrict__ xb,
    const float* __restrict__ wq, const float* __restrict__ wk,
    const float* __restrict__ wv, const float* __restrict__ wo,
    u16* __restrict__ wqkvT, u16* __restrict__ woT) {
  __shared__ float t[32][33];
  const int bid = blockIdx.x, tid = threadIdx.x;
  if (bid < 8192) {
    int i = bid * 256 + tid;
    float4 v = reinterpret_cast<const float4*>(x)[i];
    ushort4 o;
    o.x = f2bf(v.x); o.y = f2bf(v.y); o.z = f2bf(v.z); o.w = f2bf(v.w);
    reinterpret_cast<ushort4*>(xb)[i] = o;
    return;
  }
  const int wb = bid - 8192;
  const int z = wb >> 10;
  const int rem = wb & 1023;
  const int bx = rem & 31, by = rem >> 5;
  const float* w = (z == 0) ? wq : (z == 1) ? wk : (z == 2) ? wv : wo;
  u16* wt = (z < 3) ? (wqkvT + (size_t)z * 1024 * 1024) : woT;
  const float sc = (z == 0) ? QSCALE : 1.0f;
  const int tx = tid & 31, ty = tid >> 5;
  const int n0 = bx * 32, k0 = by * 32;
#pragma unroll
  for (int j = 0; j < 32; j += 8)
    t[ty + j][tx] = w[(size_t)(k0 + ty + j) * D_DIM + n0 + tx];
  __syncthreads();
#pragma unroll
  for (int j = 0; j < 32; j += 8)
    wt[(size_t)(n0 + ty + j) * D_DIM + k0 + tx] = f2bf(t[tx][ty + j] * sc);
}

// ============ QKV GEMM: 128x128, BK=64 single-buffer 2-sync, T2-swizzled LDS ============
__global__ __launch_bounds__(256) void gemm_qkv_kernel(
    const u16* __restrict__ A, const u16* __restrict__ Bt,
    u16* __restrict__ Qb, u16* __restrict__ KP, u16* __restrict__ VP) {
  __shared__ u16 lA[128 * 64];
  __shared__ u16 lB[128 * 64];
  const int tid = threadIdx.x, wid = tid >> 6, lane = tid & 63;
  const int wg = blockIdx.x;                       // [0,1536)
  const int swz = (wg & 7) * 192 + (wg >> 3);      // XCD-chunk (1536 % 8 == 0)
  const int bm = swz / 24, bn = swz % 24;
  const int fr = lane & 15, fq = lane >> 4;
  const int rx = (fr & 7) << 4;                    // read-side byte XOR

  const int srow = tid >> 3;                       // 0..31
  const int schunk = (tid & 7) ^ ((tid >> 3) & 7);
  const u16* gA = A + (size_t)(bm * 128 + srow) * 1024 + schunk * 8;
  const u16* gB = Bt + (size_t)(bn * 128 + srow) * 1024 + schunk * 8;
  u16* dA = &lA[wid * 8 * 64];
  u16* dB = &lB[wid * 8 * 64];

  f32x4 acc[4][4] = {};
  const int wm = (wid >> 1) * 64, wn = (wid & 1) * 64;

  for (int k0 = 0; k0 < 1024; k0 += 64) {
#pragma unroll
    for (int p = 0; p < 4; p++) {
      gload_lds16(gA + k0 + (size_t)p * 32 * 1024, dA + p * 32 * 64);
      gload_lds16(gB + k0 + (size_t)p * 32 * 1024, dB + p * 32 * 64);
    }
    __syncthreads();
    {
      bf16x8 fa[4], fb[4];
#pragma unroll
      for (int i = 0; i < 4; i++) {
        fa[i] = *(const bf16x8*)((const char*)lA + (wm + i * 16 + fr) * 128 + ((fq << 4) ^ rx));
        fb[i] = *(const bf16x8*)((const char*)lB + (wn + i * 16 + fr) * 128 + ((fq << 4) ^ rx));
      }
#pragma unroll
      for (int i = 0; i < 4; i++)
#pragma unroll
        for (int j = 0; j < 4; j++)
          acc[i][j] = __builtin_amdgcn_mfma_f32_16x16x32_bf16(fa[i], fb[j], acc[i][j], 0, 0, 0);
    }
    {
      bf16x8 fa[4], fb[4];
#pragma unroll
      for (int i = 0; i < 4; i++) {
        fa[i] = *(const bf16x8*)((const char*)lA + (wm + i * 16 + fr) * 128 + (((4 + fq) << 4) ^ rx));
        fb[i] = *(const bf16x8*)((const char*)lB + (wn + i * 16 + fr) * 128 + (((4 + fq) << 4) ^ rx));
      }
#pragma unroll
      for (int i = 0; i < 4; i++)
#pragma unroll
        for (int j = 0; j < 4; j++)
          acc[i][j] = __builtin_amdgcn_mfma_f32_16x16x32_bf16(fa[i], fb[j], acc[i][j], 0, 0, 0);
    }
    __syncthreads();
  }

  const int col0 = bn * 128;   // wave-uniform region select
  if (col0 < 1024) {
#pragma unroll
    for (int i = 0; i < 4; i++)
#pragma unroll
      for (int j = 0; j < 4; j++)
#pragma unroll
        for (int r = 0; r < 4; r++) {
          int row = bm * 128 + wm + i * 16 + fq * 4 + r;
          int col = col0 + wn + j * 16 + fr;
          Qb[(size_t)row * 1024 + col] = f2bf(acc[i][j][r]);
        }
  } else if (col0 < 2048) {
#pragma unroll
    for (int i = 0; i < 4; i++)
#pragma unroll
      for (int j = 0; j < 4; j++) {
        int col = col0 + wn + j * 16 + fr;
        int ck = col - 1024;
        int h = ck >> 6, d = ck & 63;
        int sfr = d >> 4, e = d & 7, hb = (d >> 3) & 1;
#pragma unroll
        for (int r = 0; r < 4; r++) {
          int row = bm * 128 + wm + i * 16 + fq * 4 + r;
          int b = row >> 11, sp = row & 2047;
          int bh = b * 16 + h, jt = sp >> 5;
          int lanep = (sp & 31) + 32 * hb;
          KP[((size_t)(bh * 64 + jt) * 4 + sfr) * 512 + lanep * 8 + e] = f2bf(acc[i][j][r]);
        }
      }
  } else {
#pragma unroll
    for (int i = 0; i < 4; i++)
#pragma unroll
      for (int j = 0; j < 4; j++) {
        int col = col0 + wn + j * 16 + fr;
        int cv = col - 2048;
        int h = cv >> 6, d = cv & 63;
        int R0 = bm * 128 + wm + i * 16 + fq * 4;
        int b = R0 >> 11, sp0 = R0 & 2047;
        int bh = b * 16 + h, jt = sp0 >> 5;
        int c = (d >> 5) * 2 + ((sp0 >> 4) & 1);
        int lanep = (d & 31) + 32 * ((sp0 >> 3) & 1);
        int e0 = sp0 & 7;
        ushort4 ov;
        ov.x = f2bf(acc[i][j][0]); ov.y = f2bf(acc[i][j][1]);
        ov.z = f2bf(acc[i][j][2]); ov.w = f2bf(acc[i][j][3]);
        *(ushort4*)(VP + ((size_t)(bh * 64 + jt) * 4 + c) * 512 + lanep * 8 + e0) = ov;
      }
  }
}

// ============ out-proj GEMM: 128x128, BK=64 single-buffer 2-sync, T2-swizzled ============
__global__ __launch_bounds__(256) void gemm_out_kernel(
    const u16* __restrict__ A, const u16* __restrict__ Bt,
    float* __restrict__ C, const float* __restrict__ bias) {
  __shared__ u16 lA[128 * 64];
  __shared__ u16 lB[128 * 64];
  const int tid = threadIdx.x, wid = tid >> 6, lane = tid & 63;
  const int wg = blockIdx.x;                       // [0,512)
  const int swz = (wg & 7) * 64 + (wg >> 3);       // XCD-chunk (512 % 8 == 0)
  const int bm = swz >> 3, bn = swz & 7;
  const int fr = lane & 15, fq = lane >> 4;
  const int rx = (fr & 7) << 4;

  const int srow = tid >> 3;
  const int schunk = (tid & 7) ^ ((tid >> 3) & 7);
  const u16* gA = A + (size_t)(bm * 128 + srow) * 1024 + schunk * 8;
  const u16* gB = Bt + (size_t)(bn * 128 + srow) * 1024 + schunk * 8;
  u16* dA = &lA[wid * 8 * 64];
  u16* dB = &lB[wid * 8 * 64];

  f32x4 acc[4][4] = {};
  const int wm = (wid >> 1) * 64, wn = (wid & 1) * 64;

  for (int k0 = 0; k0 < 1024; k0 += 64) {
#pragma unroll
    for (int p = 0; p < 4; p++) {
      gload_lds16(gA + k0 + (size_t)p * 32 * 1024, dA + p * 32 * 64);
      gload_lds16(gB + k0 + (size_t)p * 32 * 1024, dB + p * 32 * 64);
    }
    __syncthreads();
    {
      bf16x8 fa[4], fb[4];
#pragma unroll
      for (int i = 0; i < 4; i++) {
        fa[i] = *(const bf16x8*)((const char*)lA + (wm + i * 16 + fr) * 128 + ((fq << 4) ^ rx));
        fb[i] = *(const bf16x8*)((const char*)lB + (wn + i * 16 + fr) * 128 + ((fq << 4) ^ rx));
      }
#pragma unroll
      for (int i = 0; i < 4; i++)
#pragma unroll
        for (int j = 0; j < 4; j++)
          acc[i][j] = __builtin_amdgcn_mfma_f32_16x16x32_bf16(fa[i], fb[j], acc[i][j], 0, 0, 0);
    }
    {
      bf16x8 fa[4], fb[4];
#pragma unroll
      for (int i = 0; i < 4; i++) {
        fa[i] = *(const bf16x8*)((const char*)lA + (wm + i * 16 + fr) * 128 + (((4 + fq) << 4) ^ rx));
        fb[i] = *(const bf16x8*)((const char*)lB + (wn + i * 16 + fr) * 128 + (((4 + fq) << 4) ^ rx));
      }
#pragma unroll
      for (int i = 0; i < 4; i++)
#pragma unroll
        for (int j = 0; j < 4; j++)
          acc[i][j] = __builtin_amdgcn_mfma_f32_16x16x32_bf16(fa[i], fb[j], acc[i][j], 0, 0, 0);
    }
    __syncthreads();
  }

#pragma unroll
  for (int i = 0; i < 4; i++)
#pragma unroll
    for (int j = 0; j < 4; j++)
#pragma unroll
      for (int r = 0; r < 4; r++) {
        int row = bm * 128 + wm + i * 16 + fq * 4 + r;
        int col = bn * 128 + wn + j * 16 + fr;
        C[(size_t)row * 1024 + col] = acc[i][j][r] + bias[col];
      }
}

// ---------------- flash attention (causal), swapped-operand 32x32 MFMA ----------------
// qblk permutation balances per-CU resident work: CU c hosts g in {c>>3, +4, +8, +12};
// P chosen so each such quad's qblk sum == 30 (was 28..40 -> +-18% imbalance).
__global__ __launch_bounds__(256) void attn_kernel(
    const u16* __restrict__ Q, const u16* __restrict__ KP,
    const u16* __restrict__ VP, u16* __restrict__ O) {
  const int tid = threadIdx.x, wid = tid >> 6, lane = tid & 63;
  const int lq = lane & 31, hi = lane >> 5;
  int f = blockIdx.x;
  int xcd = f & 7, kk = f >> 3;
  int bh = xcd * 8 + (kk & 7);
  // balanced qblk permutation: g>>2==0 -> 15-2gg; 1 -> 2gg; 2 -> 14-2gg; 3 -> 2gg+1
  int g = kk >> 3, gg = g & 3, gq = g >> 2;
  int qblk = (gq == 0) ? 15 - 2 * gg
           : (gq == 1) ? 2 * gg
           : (gq == 2) ? 14 - 2 * gg
                       : 2 * gg + 1;
  int b = bh >> 4, h = bh & 15;
  int q0 = qblk * 128 + wid * 32;
  int q = q0 + lq;

  const u16* Qrow = Q + (size_t)(b * S_LEN + q) * D_DIM + h * HDIM;
  bf16x8 qf[4];
#pragma unroll
  for (int s = 0; s < 4; s++)
    qf[s] = *(const bf16x8*)(Qrow + s * 16 + hi * 8);

  const bf16x8* KPt = (const bf16x8*)KP + (size_t)bh * 64 * 4 * 64;
  const bf16x8* VPt = (const bf16x8*)VP + (size_t)bh * 64 * 4 * 64;

  f32x16 acc0 = {}, acc1 = {};
  float m = -3.0e38f, l = 0.f;
  const int nt = qblk * 4 + wid + 1;

  for (int t = 0; t < nt; ++t) {
    const int j0 = t * 32;
    const size_t fb = (size_t)t * 4 * 64 + lane;
    bf16x8 kf0 = KPt[fb], kf1 = KPt[fb + 64], kf2 = KPt[fb + 128], kf3 = KPt[fb + 192];
    bf16x8 vf00 = VPt[fb], vf01 = VPt[fb + 64], vf10 = VPt[fb + 128], vf11 = VPt[fb + 192];

    f32x16 sa = {};
    __builtin_amdgcn_s_setprio(1);
    sa = __builtin_amdgcn_mfma_f32_32x32x16_bf16(kf0, qf[0], sa, 0, 0, 0);
    sa = __builtin_amdgcn_mfma_f32_32x32x16_bf16(kf1, qf[1], sa, 0, 0, 0);
    sa = __builtin_amdgcn_mfma_f32_32x32x16_bf16(kf2, qf[2], sa, 0, 0, 0);
    sa = __builtin_amdgcn_mfma_f32_32x32x16_bf16(kf3, qf[3], sa, 0, 0, 0);
    __builtin_amdgcn_s_setprio(0);

    float p[16];
#pragma unroll
    for (int r = 0; r < 16; ++r) p[r] = sa[r];

    if (t == nt - 1) {
#pragma unroll
      for (int r = 0; r < 16; ++r) {
        int kidx = j0 + (r & 3) + 8 * (r >> 2) + 4 * hi;
        if (kidx > q) p[r] = -3.0e38f;
      }
    }

    float x8[8], x4[4], x2[2];
#pragma unroll
    for (int i = 0; i < 8; ++i) x8[i] = fmaxf(p[2 * i], p[2 * i + 1]);
#pragma unroll
    for (int i = 0; i < 4; ++i) x4[i] = fmaxf(x8[2 * i], x8[2 * i + 1]);
    x2[0] = fmaxf(x4[0], x4[1]); x2[1] = fmaxf(x4[2], x4[3]);
    float pm = fmaxf(x2[0], x2[1]);
    pm = fmaxf(pm, __shfl_xor(pm, 32));

    if (__any(pm > m + 11.5f)) {
      float mn = fmaxf(m, pm);
      float sc = EXP2(m - mn);
      l *= sc;
#pragma unroll
      for (int r = 0; r < 16; ++r) { acc0[r] *= sc; acc1[r] *= sc; }
      m = mn;
    }

    float rs = 0.f;
#pragma unroll
    for (int r = 0; r < 16; ++r) { p[r] = EXP2(p[r] - m); rs += p[r]; }
    rs += __shfl_xor(rs, 32);
    l += rs;

    unsigned c0 = cvtpk(p[0],  p[1]),  c1 = cvtpk(p[2],  p[3]);
    unsigned c2 = cvtpk(p[4],  p[5]),  c3 = cvtpk(p[6],  p[7]);
    unsigned c4 = cvtpk(p[8],  p[9]),  c5 = cvtpk(p[10], p[11]);
    unsigned c6 = cvtpk(p[12], p[13]), c7 = cvtpk(p[14], p[15]);
    perm32swap(c0, c2); perm32swap(c1, c3);
    perm32swap(c4, c6); perm32swap(c5, c7);
    union U4 { unsigned u[4]; bf16x8 v; } F0, F1;
    F0.u[0] = c0; F0.u[1] = c1; F0.u[2] = c2; F0.u[3] = c3;
    F1.u[0] = c4; F1.u[1] = c5; F1.u[2] = c6; F1.u[3] = c7;

    __builtin_amdgcn_s_setprio(1);
    acc0 = __builtin_amdgcn_mfma_f32_32x32x16_bf16(vf00, F0.v, acc0, 0, 0, 0);
    acc0 = __builtin_amdgcn_mfma_f32_32x32x16_bf16(vf01, F1.v, acc0, 0, 0, 0);
    acc1 = __builtin_amdgcn_mfma_f32_32x32x16_bf16(vf10, F0.v, acc1, 0, 0, 0);
    acc1 = __builtin_amdgcn_mfma_f32_32x32x16_bf16(vf11, F1.v, acc1, 0, 0, 0);
    __builtin_amdgcn_s_setprio(0);
  }

  float inv = 1.f / l;
  u16* Orow = O + (size_t)(b * S_LEN + q) * D_DIM + h * HDIM;
#pragma unroll
  for (int g2 = 0; g2 < 4; ++g2) {
    ushort4 o4;
    o4.x = f2bf(acc0[g2 * 4 + 0] * inv);
    o4.y = f2bf(acc0[g2 * 4 + 1] * inv);
    o4.z = f2bf(acc0[g2 * 4 + 2] * inv);
    o4.w = f2bf(acc0[g2 * 4 + 3] * inv);
    *(ushort4*)(Orow + 8 * g2 + 4 * hi) = o4;
  }
#pragma unroll
  for (int g2 = 0; g2 < 4; ++g2) {
    ushort4 o4;
    o4.x = f2bf(acc1[g2 * 4 + 0] * inv);
    o4.y = f2bf(acc1[g2 * 4 + 1] * inv);
    o4.z = f2bf(acc1[g2 * 4 + 2] * inv);
    o4.w = f2bf(acc1[g2 * 4 + 3] * inv);
    *(ushort4*)(Orow + 32 + 8 * g2 + 4 * hi) = o4;
  }
}

// ---------------- launcher ----------------
extern "C" void kernel_launch(void* const* d_in, const int* in_sizes, int n_in,
                              void* d_out, int out_size, void* d_ws, size_t ws_size,
                              hipStream_t stream) {
  const float* x  = (const float*)d_in[0];
  const float* wq = (const float*)d_in[1];
  const float* wk = (const float*)d_in[2];
  const float* wv = (const float*)d_in[3];
  const float* wo = (const float*)d_in[4];
  const float* ob = (const float*)d_in[5];
  float* out = (float*)d_out;

  char* ws = (char*)d_ws;
  u16* Xb    = (u16*)(ws);                              // slot A: Xb then Ab
  u16* Ab    = (u16*)(ws);
  u16* Qb    = (u16*)(ws + (size_t)16 * 1024 * 1024);   // 16 MB
  u16* KPb   = (u16*)(ws + (size_t)32 * 1024 * 1024);   // 16 MB
  u16* VPb   = (u16*)(ws + (size_t)48 * 1024 * 1024);   // 16 MB
  u16* WqkvT = (u16*)(ws + (size_t)64 * 1024 * 1024);   // 6 MB
  u16* WoT   = (u16*)(ws + (size_t)70 * 1024 * 1024);   // 2 MB

  // fused prep: X convert (8192 blocks) + 4 weight transposes (4096 blocks)
  prep_kernel<<<dim3(12288), 256, 0, stream>>>(x, Xb, wq, wk, wv, wo, WqkvT, WoT);

  // fused QKV projection [8192,1024]x[1024,3072] with fused Q/K/V pack epilogue
  gemm_qkv_kernel<<<dim3(1536), 256, 0, stream>>>(Xb, WqkvT, Qb, KPb, VPb);

  attn_kernel<<<dim3(1024), 256, 0, stream>>>(Qb, KPb, VPb, Ab);

  // out projection [8192,1024]x[1024,1024] + bias, fp32 out
  gemm_out_kernel<<<dim3(512), 256, 0, stream>>>(Ab, WoT, out, ob);
}

// Round 17
// 164.708 us; speedup vs baseline: 1.0571x; 1.0571x over previous
//
#include <hip/hip_runtime.h>
#include <hip/hip_bf16.h>

#define S_LEN 2048
#define D_DIM 1024
#define NHEAD 16
#define HDIM  64
#define BATCH 4
#define MROWS (BATCH*S_LEN)   /* 8192 */

typedef short bf16x8 __attribute__((ext_vector_type(8)));
typedef float f32x4  __attribute__((ext_vector_type(4)));
typedef float f32x16 __attribute__((ext_vector_type(16)));
typedef unsigned short u16;

#if __has_builtin(__builtin_amdgcn_exp2f)
#define EXP2(x) __builtin_amdgcn_exp2f(x)
#else
#define EXP2(x) __expf((x) * 0.6931471805599453f)
#endif

#define QSCALE 0.1803368801111137f   /* (1/8) * log2(e) */

__device__ inline u16 f2bf(float f) {
  union { float f; unsigned u; } v; v.f = f;
  unsigned r = v.u + 0x7fff + ((v.u >> 16) & 1);   // RNE
  return (u16)(r >> 16);
}

__device__ inline unsigned cvtpk(float lo, float hi_) {
  unsigned d;
  asm("v_cvt_pk_bf16_f32 %0, %1, %2" : "=v"(d) : "v"(lo), "v"(hi_));
  return d;
}

__device__ inline void perm32swap(unsigned& a, unsigned& b) {
  asm volatile("v_permlane32_swap_b32 %0, %1" : "+v"(a), "+v"(b));
}

__device__ inline void gload_lds16(const void* g, void* l) {
  __builtin_amdgcn_global_load_lds(
      (const __attribute__((address_space(1))) void*)g,
      (__attribute__((address_space(3))) void*)l, 16, 0, 0);
}

// ---------------- fused prep: X fp32->bf16 + 4 weight transposes ----------------
__global__ __launch_bounds__(256) void prep_kernel(
    const float* __restrict__ x, u16* __restrict__ xb,
    const float* __restrict__ wq, const float* __restrict__ wk,
    const float* __restrict__ wv, const float* __restrict__ wo,
    u16* __restrict__ wqkvT, u16* __restrict__ woT) {
  __shared__ float t[32][33];
  const int bid = blockIdx.x, tid = threadIdx.x;
  if (bid < 8192) {
    int i = bid * 256 + tid;
    float4 v = reinterpret_cast<const float4*>(x)[i];
    ushort4 o;
    o.x = f2bf(v.x); o.y = f2bf(v.y); o.z = f2bf(v.z); o.w = f2bf(v.w);
    reinterpret_cast<ushort4*>(xb)[i] = o;
    return;
  }
  const int wb = bid - 8192;
  const int z = wb >> 10;
  const int rem = wb & 1023;
  const int bx = rem & 31, by = rem >> 5;
  const float* w = (z == 0) ? wq : (z == 1) ? wk : (z == 2) ? wv : wo;
  u16* wt = (z < 3) ? (wqkvT + (size_t)z * 1024 * 1024) : woT;
  const float sc = (z == 0) ? QSCALE : 1.0f;
  const int tx = tid & 31, ty = tid >> 5;
  const int n0 = bx * 32, k0 = by * 32;
#pragma unroll
  for (int j = 0; j < 32; j += 8)
    t[ty + j][tx] = w[(size_t)(k0 + ty + j) * D_DIM + n0 + tx];
  __syncthreads();
#pragma unroll
  for (int j = 0; j < 32; j += 8)
    wt[(size_t)(n0 + ty + j) * D_DIM + k0 + tx] = f2bf(t[tx][ty + j] * sc);
}

// ============ QKV GEMM: 128x128, BK=64 single-buffer 2-sync, T2-swizzled LDS ============
__global__ __launch_bounds__(256) void gemm_qkv_kernel(
    const u16* __restrict__ A, const u16* __restrict__ Bt,
    u16* __restrict__ Qb, u16* __restrict__ KP, u16* __restrict__ VP) {
  __shared__ u16 lA[128 * 64];
  __shared__ u16 lB[128 * 64];
  const int tid = threadIdx.x, wid = tid >> 6, lane = tid & 63;
  const int wg = blockIdx.x;                       // [0,1536)
  const int swz = (wg & 7) * 192 + (wg >> 3);      // XCD-chunk (1536 % 8 == 0)
  const int bm = swz / 24, bn = swz % 24;
  const int fr = lane & 15, fq = lane >> 4;
  const int rx = (fr & 7) << 4;                    // read-side byte XOR

  const int srow = tid >> 3;                       // 0..31
  const int schunk = (tid & 7) ^ ((tid >> 3) & 7);
  const u16* gA = A + (size_t)(bm * 128 + srow) * 1024 + schunk * 8;
  const u16* gB = Bt + (size_t)(bn * 128 + srow) * 1024 + schunk * 8;
  u16* dA = &lA[wid * 8 * 64];
  u16* dB = &lB[wid * 8 * 64];

  f32x4 acc[4][4] = {};
  const int wm = (wid >> 1) * 64, wn = (wid & 1) * 64;

  for (int k0 = 0; k0 < 1024; k0 += 64) {
#pragma unroll
    for (int p = 0; p < 4; p++) {
      gload_lds16(gA + k0 + (size_t)p * 32 * 1024, dA + p * 32 * 64);
      gload_lds16(gB + k0 + (size_t)p * 32 * 1024, dB + p * 32 * 64);
    }
    __syncthreads();
    {
      bf16x8 fa[4], fb[4];
#pragma unroll
      for (int i = 0; i < 4; i++) {
        fa[i] = *(const bf16x8*)((const char*)lA + (wm + i * 16 + fr) * 128 + ((fq << 4) ^ rx));
        fb[i] = *(const bf16x8*)((const char*)lB + (wn + i * 16 + fr) * 128 + ((fq << 4) ^ rx));
      }
#pragma unroll
      for (int i = 0; i < 4; i++)
#pragma unroll
        for (int j = 0; j < 4; j++)
          acc[i][j] = __builtin_amdgcn_mfma_f32_16x16x32_bf16(fa[i], fb[j], acc[i][j], 0, 0, 0);
    }
    {
      bf16x8 fa[4], fb[4];
#pragma unroll
      for (int i = 0; i < 4; i++) {
        fa[i] = *(const bf16x8*)((const char*)lA + (wm + i * 16 + fr) * 128 + (((4 + fq) << 4) ^ rx));
        fb[i] = *(const bf16x8*)((const char*)lB + (wn + i * 16 + fr) * 128 + (((4 + fq) << 4) ^ rx));
      }
#pragma unroll
      for (int i = 0; i < 4; i++)
#pragma unroll
        for (int j = 0; j < 4; j++)
          acc[i][j] = __builtin_amdgcn_mfma_f32_16x16x32_bf16(fa[i], fb[j], acc[i][j], 0, 0, 0);
    }
    __syncthreads();
  }

  const int col0 = bn * 128;   // wave-uniform region select
  if (col0 < 1024) {
#pragma unroll
    for (int i = 0; i < 4; i++)
#pragma unroll
      for (int j = 0; j < 4; j++)
#pragma unroll
        for (int r = 0; r < 4; r++) {
          int row = bm * 128 + wm + i * 16 + fq * 4 + r;
          int col = col0 + wn + j * 16 + fr;
          Qb[(size_t)row * 1024 + col] = f2bf(acc[i][j][r]);
        }
  } else if (col0 < 2048) {
#pragma unroll
    for (int i = 0; i < 4; i++)
#pragma unroll
      for (int j = 0; j < 4; j++) {
        int col = col0 + wn + j * 16 + fr;
        int ck = col - 1024;
        int h = ck >> 6, d = ck & 63;
        int sfr = d >> 4, e = d & 7, hb = (d >> 3) & 1;
#pragma unroll
        for (int r = 0; r < 4; r++) {
          int row = bm * 128 + wm + i * 16 + fq * 4 + r;
          int b = row >> 11, sp = row & 2047;
          int bh = b * 16 + h, jt = sp >> 5;
          int lanep = (sp & 31) + 32 * hb;
          KP[((size_t)(bh * 64 + jt) * 4 + sfr) * 512 + lanep * 8 + e] = f2bf(acc[i][j][r]);
        }
      }
  } else {
#pragma unroll
    for (int i = 0; i < 4; i++)
#pragma unroll
      for (int j = 0; j < 4; j++) {
        int col = col0 + wn + j * 16 + fr;
        int cv = col - 2048;
        int h = cv >> 6, d = cv & 63;
        int R0 = bm * 128 + wm + i * 16 + fq * 4;
        int b = R0 >> 11, sp0 = R0 & 2047;
        int bh = b * 16 + h, jt = sp0 >> 5;
        int c = (d >> 5) * 2 + ((sp0 >> 4) & 1);
        int lanep = (d & 31) + 32 * ((sp0 >> 3) & 1);
        int e0 = sp0 & 7;
        ushort4 ov;
        ov.x = f2bf(acc[i][j][0]); ov.y = f2bf(acc[i][j][1]);
        ov.z = f2bf(acc[i][j][2]); ov.w = f2bf(acc[i][j][3]);
        *(ushort4*)(VP + ((size_t)(bh * 64 + jt) * 4 + c) * 512 + lanep * 8 + e0) = ov;
      }
  }
}

// ============ out-proj GEMM: 128x128, BK=64 single-buffer 2-sync, T2-swizzled ============
__global__ __launch_bounds__(256) void gemm_out_kernel(
    const u16* __restrict__ A, const u16* __restrict__ Bt,
    float* __restrict__ C, const float* __restrict__ bias) {
  __shared__ u16 lA[128 * 64];
  __shared__ u16 lB[128 * 64];
  const int tid = threadIdx.x, wid = tid >> 6, lane = tid & 63;
  const int wg = blockIdx.x;                       // [0,512)
  const int swz = (wg & 7) * 64 + (wg >> 3);       // XCD-chunk (512 % 8 == 0)
  const int bm = swz >> 3, bn = swz & 7;
  const int fr = lane & 15, fq = lane >> 4;
  const int rx = (fr & 7) << 4;

  const int srow = tid >> 3;
  const int schunk = (tid & 7) ^ ((tid >> 3) & 7);
  const u16* gA = A + (size_t)(bm * 128 + srow) * 1024 + schunk * 8;
  const u16* gB = Bt + (size_t)(bn * 128 + srow) * 1024 + schunk * 8;
  u16* dA = &lA[wid * 8 * 64];
  u16* dB = &lB[wid * 8 * 64];

  f32x4 acc[4][4] = {};
  const int wm = (wid >> 1) * 64, wn = (wid & 1) * 64;

  for (int k0 = 0; k0 < 1024; k0 += 64) {
#pragma unroll
    for (int p = 0; p < 4; p++) {
      gload_lds16(gA + k0 + (size_t)p * 32 * 1024, dA + p * 32 * 64);
      gload_lds16(gB + k0 + (size_t)p * 32 * 1024, dB + p * 32 * 64);
    }
    __syncthreads();
    {
      bf16x8 fa[4], fb[4];
#pragma unroll
      for (int i = 0; i < 4; i++) {
        fa[i] = *(const bf16x8*)((const char*)lA + (wm + i * 16 + fr) * 128 + ((fq << 4) ^ rx));
        fb[i] = *(const bf16x8*)((const char*)lB + (wn + i * 16 + fr) * 128 + ((fq << 4) ^ rx));
      }
#pragma unroll
      for (int i = 0; i < 4; i++)
#pragma unroll
        for (int j = 0; j < 4; j++)
          acc[i][j] = __builtin_amdgcn_mfma_f32_16x16x32_bf16(fa[i], fb[j], acc[i][j], 0, 0, 0);
    }
    {
      bf16x8 fa[4], fb[4];
#pragma unroll
      for (int i = 0; i < 4; i++) {
        fa[i] = *(const bf16x8*)((const char*)lA + (wm + i * 16 + fr) * 128 + (((4 + fq) << 4) ^ rx));
        fb[i] = *(const bf16x8*)((const char*)lB + (wn + i * 16 + fr) * 128 + (((4 + fq) << 4) ^ rx));
      }
#pragma unroll
      for (int i = 0; i < 4; i++)
#pragma unroll
        for (int j = 0; j < 4; j++)
          acc[i][j] = __builtin_amdgcn_mfma_f32_16x16x32_bf16(fa[i], fb[j], acc[i][j], 0, 0, 0);
    }
    __syncthreads();
  }

#pragma unroll
  for (int i = 0; i < 4; i++)
#pragma unroll
    for (int j = 0; j < 4; j++)
#pragma unroll
      for (int r = 0; r < 4; r++) {
        int row = bm * 128 + wm + i * 16 + fq * 4 + r;
        int col = bn * 128 + wn + j * 16 + fr;
        C[(size_t)row * 1024 + col] = acc[i][j][r] + bias[col];
      }
}

// ---------------- flash attention (causal), swapped-operand 32x32 MFMA (R15 form) ----------------
// Big-first dispatch ordering (qblk = 15 - (kk>>3)) — measured best of 4 schedules.
__global__ __launch_bounds__(256) void attn_kernel(
    const u16* __restrict__ Q, const u16* __restrict__ KP,
    const u16* __restrict__ VP, u16* __restrict__ O) {
  const int tid = threadIdx.x, wid = tid >> 6, lane = tid & 63;
  const int lq = lane & 31, hi = lane >> 5;
  int f = blockIdx.x;
  int xcd = f & 7, kk = f >> 3;
  int bh = xcd * 8 + (kk & 7);
  int qblk = 15 - (kk >> 3);
  int b = bh >> 4, h = bh & 15;
  int q0 = qblk * 128 + wid * 32;
  int q = q0 + lq;

  const u16* Qrow = Q + (size_t)(b * S_LEN + q) * D_DIM + h * HDIM;
  bf16x8 qf[4];
#pragma unroll
  for (int s = 0; s < 4; s++)
    qf[s] = *(const bf16x8*)(Qrow + s * 16 + hi * 8);

  const bf16x8* KPt = (const bf16x8*)KP + (size_t)bh * 64 * 4 * 64;
  const bf16x8* VPt = (const bf16x8*)VP + (size_t)bh * 64 * 4 * 64;

  f32x16 acc0 = {}, acc1 = {};
  float m = -3.0e38f, l = 0.f;
  const int nt = qblk * 4 + wid + 1;

  for (int t = 0; t < nt; ++t) {
    const int j0 = t * 32;
    const size_t fb = (size_t)t * 4 * 64 + lane;
    bf16x8 kf0 = KPt[fb], kf1 = KPt[fb + 64], kf2 = KPt[fb + 128], kf3 = KPt[fb + 192];
    bf16x8 vf00 = VPt[fb], vf01 = VPt[fb + 64], vf10 = VPt[fb + 128], vf11 = VPt[fb + 192];

    f32x16 sa = {};
    __builtin_amdgcn_s_setprio(1);
    sa = __builtin_amdgcn_mfma_f32_32x32x16_bf16(kf0, qf[0], sa, 0, 0, 0);
    sa = __builtin_amdgcn_mfma_f32_32x32x16_bf16(kf1, qf[1], sa, 0, 0, 0);
    sa = __builtin_amdgcn_mfma_f32_32x32x16_bf16(kf2, qf[2], sa, 0, 0, 0);
    sa = __builtin_amdgcn_mfma_f32_32x32x16_bf16(kf3, qf[3], sa, 0, 0, 0);
    __builtin_amdgcn_s_setprio(0);

    float p[16];
#pragma unroll
    for (int r = 0; r < 16; ++r) p[r] = sa[r];

    if (t == nt - 1) {
#pragma unroll
      for (int r = 0; r < 16; ++r) {
        int kidx = j0 + (r & 3) + 8 * (r >> 2) + 4 * hi;
        if (kidx > q) p[r] = -3.0e38f;
      }
    }

    float x8[8], x4[4], x2[2];
#pragma unroll
    for (int i = 0; i < 8; ++i) x8[i] = fmaxf(p[2 * i], p[2 * i + 1]);
#pragma unroll
    for (int i = 0; i < 4; ++i) x4[i] = fmaxf(x8[2 * i], x8[2 * i + 1]);
    x2[0] = fmaxf(x4[0], x4[1]); x2[1] = fmaxf(x4[2], x4[3]);
    float pm = fmaxf(x2[0], x2[1]);
    pm = fmaxf(pm, __shfl_xor(pm, 32));

    if (__any(pm > m + 11.5f)) {
      float mn = fmaxf(m, pm);
      float sc = EXP2(m - mn);
      l *= sc;
#pragma unroll
      for (int r = 0; r < 16; ++r) { acc0[r] *= sc; acc1[r] *= sc; }
      m = mn;
    }

    float rs = 0.f;
#pragma unroll
    for (int r = 0; r < 16; ++r) { p[r] = EXP2(p[r] - m); rs += p[r]; }
    rs += __shfl_xor(rs, 32);
    l += rs;

    unsigned c0 = cvtpk(p[0],  p[1]),  c1 = cvtpk(p[2],  p[3]);
    unsigned c2 = cvtpk(p[4],  p[5]),  c3 = cvtpk(p[6],  p[7]);
    unsigned c4 = cvtpk(p[8],  p[9]),  c5 = cvtpk(p[10], p[11]);
    unsigned c6 = cvtpk(p[12], p[13]), c7 = cvtpk(p[14], p[15]);
    perm32swap(c0, c2); perm32swap(c1, c3);
    perm32swap(c4, c6); perm32swap(c5, c7);
    union U4 { unsigned u[4]; bf16x8 v; } F0, F1;
    F0.u[0] = c0; F0.u[1] = c1; F0.u[2] = c2; F0.u[3] = c3;
    F1.u[0] = c4; F1.u[1] = c5; F1.u[2] = c6; F1.u[3] = c7;

    __builtin_amdgcn_s_setprio(1);
    acc0 = __builtin_amdgcn_mfma_f32_32x32x16_bf16(vf00, F0.v, acc0, 0, 0, 0);
    acc0 = __builtin_amdgcn_mfma_f32_32x32x16_bf16(vf01, F1.v, acc0, 0, 0, 0);
    acc1 = __builtin_amdgcn_mfma_f32_32x32x16_bf16(vf10, F0.v, acc1, 0, 0, 0);
    acc1 = __builtin_amdgcn_mfma_f32_32x32x16_bf16(vf11, F1.v, acc1, 0, 0, 0);
    __builtin_amdgcn_s_setprio(0);
  }

  float inv = 1.f / l;
  u16* Orow = O + (size_t)(b * S_LEN + q) * D_DIM + h * HDIM;
#pragma unroll
  for (int g = 0; g < 4; ++g) {
    ushort4 o4;
    o4.x = f2bf(acc0[g * 4 + 0] * inv);
    o4.y = f2bf(acc0[g * 4 + 1] * inv);
    o4.z = f2bf(acc0[g * 4 + 2] * inv);
    o4.w = f2bf(acc0[g * 4 + 3] * inv);
    *(ushort4*)(Orow + 8 * g + 4 * hi) = o4;
  }
#pragma unroll
  for (int g = 0; g < 4; ++g) {
    ushort4 o4;
    o4.x = f2bf(acc1[g * 4 + 0] * inv);
    o4.y = f2bf(acc1[g * 4 + 1] * inv);
    o4.z = f2bf(acc1[g * 4 + 2] * inv);
    o4.w = f2bf(acc1[g * 4 + 3] * inv);
    *(ushort4*)(Orow + 32 + 8 * g + 4 * hi) = o4;
  }
}

// ---------------- launcher ----------------
extern "C" void kernel_launch(void* const* d_in, const int* in_sizes, int n_in,
                              void* d_out, int out_size, void* d_ws, size_t ws_size,
                              hipStream_t stream) {
  const float* x  = (const float*)d_in[0];
  const float* wq = (const float*)d_in[1];
  const float* wk = (const float*)d_in[2];
  const float* wv = (const float*)d_in[3];
  const float* wo = (const float*)d_in[4];
  const float* ob = (const float*)d_in[5];
  float* out = (float*)d_out;

  char* ws = (char*)d_ws;
  u16* Xb    = (u16*)(ws);                              // slot A: Xb then Ab
  u16* Ab    = (u16*)(ws);
  u16* Qb    = (u16*)(ws + (size_t)16 * 1024 * 1024);   // 16 MB
  u16* KPb   = (u16*)(ws + (size_t)32 * 1024 * 1024);   // 16 MB
  u16* VPb   = (u16*)(ws + (size_t)48 * 1024 * 1024);   // 16 MB
  u16* WqkvT = (u16*)(ws + (size_t)64 * 1024 * 1024);   // 6 MB
  u16* WoT   = (u16*)(ws + (size_t)70 * 1024 * 1024);   // 2 MB

  // fused prep: X convert (8192 blocks) + 4 weight transposes (4096 blocks)
  prep_kernel<<<dim3(12288), 256, 0, stream>>>(x, Xb, wq, wk, wv, wo, WqkvT, WoT);

  // fused QKV projection [8192,1024]x[1024,3072] with fused Q/K/V pack epilogue
  gemm_qkv_kernel<<<dim3(1536), 256, 0, stream>>>(Xb, WqkvT, Qb, KPb, VPb);

  attn_kernel<<<dim3(1024), 256, 0, stream>>>(Qb, KPb, VPb, Ab);

  // out projection [8192,1024]x[1024,1024] + bias, fp32 out
  gemm_out_kernel<<<dim3(512), 256, 0, stream>>>(Ab, WoT, out, ob);
}